// Round 13
// baseline (14.880 us; speedup 1.0000x reference)
//
#include <hip/hip_runtime.h>
#include <hip/hip_bf16.h>
#include <math.h>

// HyperbolicDistanceHead: out[r][c] = -(2/sqrt(c))*atanh(clip(sqrt(c)*||mobius(-x,p)||, 0, 1-1e-5))
// B=128, C=4096, D=1024, c=0.5.  Single launch, no workspace.
// r7 geometry (best: 13.3us): 512 blocks x 256 thr (2/CU); block = 64 rows x 16 cols;
// wave = 16x16 full-K.  CHANGE vs r7: p is staged WHOLE-K in the prologue
// (16 VMEM/thread, one burst; SSQ+cvt+ds_write once) -> the 8-chunk loop stages
// ONLY x (8 f32x4 + 4 ds_write + SSQ per thread) -> per-chunk barrier window ~45%
// lighter, p-load latency out of the loop.  LDS 64.3 KB -> still 2 blocks/CU.
// All proven maps unchanged: XOR-swz write/read, m89 C-layout, exact fp32 norms.

#define DDIM 1024
#define CDIM 4096

using f32x4  = __attribute__((ext_vector_type(4))) float;
using bf16x8 = __attribute__((ext_vector_type(8))) short;

__device__ inline ushort toBfU(float f) {
  __hip_bfloat16 h = __float2bfloat16(f);
  return *reinterpret_cast<ushort*>(&h);
}

__global__ __launch_bounds__(256, 2) void hyper_phoist(
    const float* __restrict__ x, const float* __restrict__ p,
    float* __restrict__ out) {
  __shared__ __align__(16) char xs[2][16384];   // [buf][64 rows][256 B], XOR-swz
  __shared__ __align__(16) char ps[32768];      // [16 cols][2048 B] whole-K, XOR-swz
  __shared__ float x2s[64], p2s[16];

  const int tid  = threadIdx.x;
  const int lane = tid & 63;
  const int w    = __builtin_amdgcn_readfirstlane(tid >> 6);  // 0..3
  const int r15  = lane & 15, g = lane >> 4;

  // bijective XCD chunk swizzle (512 % 8 == 0)
  const int bid  = blockIdx.x;
  const int swz  = ((bid & 7) << 6) | (bid >> 3);
  const int cg = swz >> 1, rg = swz & 1;
  const int rbase = rg * 64, cbase = cg * 16;

  // staging thread map: tr = tid>>4 (x seg-row / p col), t16 = tid&15 (k-slot)
  const int tr  = tid >> 4;
  const int t16 = tid & 15;
  const float* gx = x + (size_t)(rbase + tr) * DDIM + t16 * 8;   // + seg*16*DDIM
  const float* gp = p + (size_t)(cbase + tr) * DDIM;
  const int xwz = (t16 << 4);                    // x write byte (pre-XOR)
  const int pswz = (tr & 7) << 4;

  float sx0 = 0.f, sx1 = 0.f, sx2 = 0.f, sx3 = 0.f, sp = 0.f;
  f32x4 acc = {0.f, 0.f, 0.f, 0.f};
  f32x4 xa[4][2];

  // A/B read bases
  const int arow = (w << 4) + r15;               // arow&7 == r15&7
  const int swr  = (r15 & 7) << 4;

#define LOADS_X(c)                                                            \
  { _Pragma("unroll")                                                         \
    for (int i = 0; i < 4; ++i) {                                             \
      xa[i][0] = *(const f32x4*)(gx + (size_t)i * 16 * DDIM + (c) * 128);     \
      xa[i][1] = *(const f32x4*)(gx + (size_t)i * 16 * DDIM + (c) * 128 + 4); \
    } }

#define SSQ4(v) (fmaf((v)[3],(v)[3],fmaf((v)[2],(v)[2],fmaf((v)[1],(v)[1],(v)[0]*(v)[0]))))

#define PACKW(a, b, dst)                                                      \
  { bf16x8 _t;                                                                \
    _t[0]=(short)toBfU((a)[0]); _t[1]=(short)toBfU((a)[1]);                   \
    _t[2]=(short)toBfU((a)[2]); _t[3]=(short)toBfU((a)[3]);                   \
    _t[4]=(short)toBfU((b)[0]); _t[5]=(short)toBfU((b)[1]);                   \
    _t[6]=(short)toBfU((b)[2]); _t[7]=(short)toBfU((b)[3]);                   \
    *(bf16x8*)(dst) = _t; }

#define WRITES_X(BUF)                                                         \
  { sx0 += SSQ4(xa[0][0]) + SSQ4(xa[0][1]);                                   \
    sx1 += SSQ4(xa[1][0]) + SSQ4(xa[1][1]);                                   \
    sx2 += SSQ4(xa[2][0]) + SSQ4(xa[2][1]);                                   \
    sx3 += SSQ4(xa[3][0]) + SSQ4(xa[3][1]);                                   \
    _Pragma("unroll")                                                         \
    for (int i = 0; i < 4; ++i) {                                             \
      const int row = i * 16 + tr;                                            \
      PACKW(xa[i][0], xa[i][1], &xs[BUF][row * 256 + (xwz ^ ((row & 7) << 4))]) \
    } }

#define COMPUTE(BUF, c)                                                       \
  { _Pragma("unroll")                                                         \
    for (int ks = 0; ks < 4; ++ks) {                                          \
      const int ao = (ks * 64 + g * 16) ^ swr;                                \
      const bf16x8 a = *(const bf16x8*)&xs[BUF][arow * 256 + ao];             \
      const bf16x8 b = *(const bf16x8*)&ps[r15 * 2048 + (((c) * 256 + ks * 64 + g * 16) ^ swr)]; \
      acc = __builtin_amdgcn_mfma_f32_16x16x32_bf16(a, b, acc, 0, 0, 0);      \
    } }

  // ---- prologue: whole-K p burst + x chunk 0
  {
    f32x4 pa[8][2];
    #pragma unroll
    for (int i = 0; i < 8; ++i) {
      pa[i][0] = *(const f32x4*)(gp + (t16 + 16 * i) * 8);
      pa[i][1] = *(const f32x4*)(gp + (t16 + 16 * i) * 8 + 4);
    }
    LOADS_X(0)
    #pragma unroll
    for (int i = 0; i < 8; ++i) {
      sp += SSQ4(pa[i][0]) + SSQ4(pa[i][1]);
      const int s = t16 + 16 * i;                 // slot 0..127
      PACKW(pa[i][0], pa[i][1], &ps[tr * 2048 + ((s << 4) ^ pswz)])
    }
    WRITES_X(0)
  }
  __syncthreads();

  // ---- main: 8 chunks of BK=128 (x only), one barrier per chunk
  #pragma unroll
  for (int c = 0; c < 8; ++c) {
    if (c < 7) LOADS_X(c + 1)        // global fp32 -> regs; hides under COMPUTE
    COMPUTE(c & 1, c)
    if (c < 7) WRITES_X((c + 1) & 1) // cvt + ds_write into the freed buffer
    __syncthreads();
  }

  // ---- exact norms: reduce 16-thread groups sharing tr (slots t16)
  #pragma unroll
  for (int off = 8; off > 0; off >>= 1) {
    sx0 += __shfl_xor(sx0, off, 64);
    sx1 += __shfl_xor(sx1, off, 64);
    sx2 += __shfl_xor(sx2, off, 64);
    sx3 += __shfl_xor(sx3, off, 64);
    sp  += __shfl_xor(sp,  off, 64);
  }
  if ((lane & 15) == 0) {
    x2s[ 0 + tr] = sx0;
    x2s[16 + tr] = sx1;
    x2s[32 + tr] = sx2;
    x2s[48 + tr] = sx3;
    p2s[tr] = sp;
  }
  __syncthreads();

  // ---- epilogue: closed-form Poincare distance, c = 0.5
  const float p2 = p2s[r15];
  #pragma unroll
  for (int i = 0; i < 4; ++i) {
    // C-frag: col = lane&15, row = (lane>>4)*4 + i (verified m89 mapping)
    const int  rloc = (w << 4) + (g << 2) + i;    // block-local row
    const float dot = acc[i];                     // <x,p>; mdot = -dot
    const float x2  = x2s[rloc];
    const float A   = 1.0f - dot + 0.5f  * p2;    // 1 + 2c*mdot + c*p2
    const float Bc  = 1.0f - 0.5f * x2;           // 1 - c*x2
    const float den = 1.0f - dot + 0.25f * x2 * p2;
    float num2 = A * A * x2 - 2.0f * A * Bc * dot + Bc * Bc * p2;
    float m2   = fmaxf(num2, 0.0f) / fmaxf(den * den, 1e-15f);
    float arg  = fminf(0.7071067811865476f * sqrtf(m2 + 1e-15f), 0.99999f);
    out[(size_t)(rbase + rloc) * CDIM + cbase + r15] =
        -1.4142135623730951f * __logf((1.0f + arg) / (1.0f - arg));
  }
}

extern "C" void kernel_launch(void* const* d_in, const int* in_sizes, int n_in,
                              void* d_out, int out_size, void* d_ws, size_t ws_size,
                              hipStream_t stream) {
  const float* x = (const float*)d_in[0];   // [128,1024] fp32
  const float* p = (const float*)d_in[1];   // [4096,1024] fp32
  float* out = (float*)d_out;               // [128,4096] fp32
  hyper_phoist<<<dim3(512), dim3(256), 0, stream>>>(x, p, out);
}